// Round 11
// baseline (112.476 us; speedup 1.0000x reference)
//
#include <hip/hip_runtime.h>

// KeySegPred — round 11: segment-major streaming logits (conv + wtab DELETED).
//   K1 mlp_kernel (256x512): r3-measured MFMA MLP (~24 us) -> out_ws fp32.
//   K2 logits_stream_kernel (256x1024): block j owns dense_w rows [391j, 391j+391):
//     phase 1: scan candidates (int4 loads), collect hits (idx, seg) into LDS
//     phase 2: tail features (cos/traffic/emb_cand dot + dense_b) vectorized over threads
//     phase 3: per hit, one wave: 63-lane float4 dot(dense_w[s], out[b]) + butterfly
//     dense_w rows are range-local per block -> ~1 HBM fetch per unique row.

#define BATCH 4096
#define DSEG 128
#define DS_ 258
#define DM7 512
#define DM8 256
#define NCAND 64
#define DWC 252
#define TSLOTS 96
#define SEGN 100000
#define SBLK 256
#define STHR 1024
#define ROWS_PER_BLK 391      // ceil(100000/256)
#define LISTCAP 2560          // expected ~1025 hits/block, max ~1150

typedef short bf16x8 __attribute__((ext_vector_type(8)));
typedef float f32x4 __attribute__((ext_vector_type(4)));

static __device__ __forceinline__ short f2bf(float f) {
    union { float f; unsigned u; } v; v.f = f;
    unsigned r = (v.u + 0x7FFFu + ((v.u >> 16) & 1u)) >> 16;  // RNE
    return (short)r;
}

__global__ __launch_bounds__(512) void mlp_kernel(
    const int* __restrict__ src, const int* __restrict__ dest,
    const float* __restrict__ offset,
    const float* __restrict__ emb_feat, const float* __restrict__ emb_dest,
    const float* __restrict__ w1, const float* __restrict__ b1,
    const float* __restrict__ bn_gamma, const float* __restrict__ bn_beta,
    const float* __restrict__ bn_mean, const float* __restrict__ bn_var,
    const float* __restrict__ w2, const float* __restrict__ b2,
    float* __restrict__ out_ws)
{
    __shared__ __align__(16) short hlds[16][520];
    const int tid = threadIdx.x;
    const int w    = tid >> 6;     // wave 0..7
    const int lane = tid & 63;
    const int lg   = lane >> 4;    // 0..3
    const int lr   = lane & 15;    // 0..15
    const int b0   = blockIdx.x * 16;

    const int si = src[b0 + lr];
    const int di = dest[b0 + lr];
    const float* fb = emb_feat + (size_t)si * DSEG;
    const float* db = emb_dest + (size_t)di * DSEG;
    bf16x8 a1[8];
#pragma unroll
    for (int s = 0; s < 8; ++s) {
        const float* p = (s < 4) ? (fb + s * 32 + lg * 8)
                                 : (db + (s - 4) * 32 + lg * 8);
        const float4 x = *(const float4*)p;
        const float4 y = *(const float4*)(p + 4);
        bf16x8 t;
        t[0] = f2bf(x.x); t[1] = f2bf(x.y); t[2] = f2bf(x.z); t[3] = f2bf(x.w);
        t[4] = f2bf(y.x); t[5] = f2bf(y.y); t[6] = f2bf(y.z); t[7] = f2bf(y.w);
        a1[s] = t;
    }
    float off1[4], off2[4];
#pragma unroll
    for (int q = 0; q < 4; ++q) {
        const float4 o = *(const float4*)(offset + (size_t)(b0 + lg * 4 + q) * 4);
        off1[q] = o.y; off2[q] = o.z;
    }

#pragma unroll
    for (int nt = 0; nt < 4; ++nt) {
        const int n = (w * 4 + nt) * 16 + lr;
        const float* wrow = w1 + (size_t)n * DS_;
        f32x4 acc = {0.f, 0.f, 0.f, 0.f};
#pragma unroll
        for (int s = 0; s < 8; ++s) {
            const float* p = wrow + s * 32 + lg * 8;
            const float2 x0 = *(const float2*)(p);
            const float2 x1 = *(const float2*)(p + 2);
            const float2 x2 = *(const float2*)(p + 4);
            const float2 x3 = *(const float2*)(p + 6);
            bf16x8 bb;
            bb[0] = f2bf(x0.x); bb[1] = f2bf(x0.y); bb[2] = f2bf(x1.x); bb[3] = f2bf(x1.y);
            bb[4] = f2bf(x2.x); bb[5] = f2bf(x2.y); bb[6] = f2bf(x3.x); bb[7] = f2bf(x3.y);
            acc = __builtin_amdgcn_mfma_f32_16x16x32_bf16(a1[s], bb, acc, 0, 0, 0);
        }
        const float2 wtail = *(const float2*)(wrow + 256);
        const float scale = bn_gamma[n] / sqrtf(bn_var[n] + 1e-6f);
        const float shift = bn_beta[n] - bn_mean[n] * scale;
        const float bias  = b1[n];
#pragma unroll
        for (int q = 0; q < 4; ++q) {
            float v = acc[q] + bias + off1[q] * wtail.x + off2[q] * wtail.y;
            v = fmaf(v, scale, shift);
            v = fmaxf(v, 0.f);
            hlds[lg * 4 + q][n] = f2bf(v);
        }
    }
    __syncthreads();

    bf16x8 a2[16];
#pragma unroll
    for (int s = 0; s < 16; ++s) {
        a2[s] = *(const bf16x8*)&hlds[lr][s * 32 + lg * 8];
    }
#pragma unroll
    for (int nt = 0; nt < 2; ++nt) {
        const int n = (w * 2 + nt) * 16 + lr;
        const float* wrow = w2 + (size_t)n * DM7;
        f32x4 acc = {0.f, 0.f, 0.f, 0.f};
#pragma unroll
        for (int s = 0; s < 16; ++s) {
            const float4 x = *(const float4*)(wrow + s * 32 + lg * 8);
            const float4 y = *(const float4*)(wrow + s * 32 + lg * 8 + 4);
            bf16x8 bb;
            bb[0] = f2bf(x.x); bb[1] = f2bf(x.y); bb[2] = f2bf(x.z); bb[3] = f2bf(x.w);
            bb[4] = f2bf(y.x); bb[5] = f2bf(y.y); bb[6] = f2bf(y.z); bb[7] = f2bf(y.w);
            acc = __builtin_amdgcn_mfma_f32_16x16x32_bf16(a2[s], bb, acc, 0, 0, 0);
        }
        const float bias = b2[n];
#pragma unroll
        for (int q = 0; q < 4; ++q) {
            out_ws[(size_t)(b0 + lg * 4 + q) * DM8 + n] = acc[q] + bias;
        }
    }
}

__global__ __launch_bounds__(1024) void logits_stream_kernel(
    const int* __restrict__ dest, const int* __restrict__ tt,
    const int* __restrict__ candidates,
    const float* __restrict__ dense_w, const float* __restrict__ dense_b,
    const float* __restrict__ cand_w, const float* __restrict__ cand_b,
    const float* __restrict__ segs_src, const float* __restrict__ segs_trg,
    const float* __restrict__ traffic_pop,
    const float* __restrict__ out_ws,
    float* __restrict__ logits)
{
    __shared__ int nhits;
    __shared__ unsigned list_i[LISTCAP];   // candidate flat index (b*64+m)
    __shared__ int      list_s[LISTCAP];   // segment id
    __shared__ float    list_t[LISTCAP];   // tail value
    const int tid = threadIdx.x;
    if (tid == 0) nhits = 0;
    __syncthreads();

    const int r0 = blockIdx.x * ROWS_PER_BLK;
    const int r1 = r0 + ROWS_PER_BLK;

    // ---- phase 1: scan candidates (64 iters of int4) ----
    const int4* __restrict__ c4p = (const int4*)candidates;
    for (int base = 0; base < (BATCH * NCAND) / 4; base += STHR) {
        const int4 c = c4p[base + tid];
        const unsigned i0 = (unsigned)(base + tid) * 4u;
        if (c.x >= r0 && c.x < r1) {
            const int p = atomicAdd(&nhits, 1);
            if (p < LISTCAP) { list_i[p] = i0;     list_s[p] = c.x; }
        }
        if (c.y >= r0 && c.y < r1) {
            const int p = atomicAdd(&nhits, 1);
            if (p < LISTCAP) { list_i[p] = i0 + 1; list_s[p] = c.y; }
        }
        if (c.z >= r0 && c.z < r1) {
            const int p = atomicAdd(&nhits, 1);
            if (p < LISTCAP) { list_i[p] = i0 + 2; list_s[p] = c.z; }
        }
        if (c.w >= r0 && c.w < r1) {
            const int p = atomicAdd(&nhits, 1);
            if (p < LISTCAP) { list_i[p] = i0 + 3; list_s[p] = c.w; }
        }
    }
    __syncthreads();
    const int nh = (nhits < LISTCAP) ? nhits : LISTCAP;

    // ---- phase 2: tail features, vectorized over all 1024 threads ----
    for (int e = tid; e < nh; e += STHR) {
        const unsigned i = list_i[e];
        const int s = list_s[e];
        const int b = (int)(i >> 6);
        const float4 t4 = *(const float4*)(out_ws + (size_t)b * DM8 + DWC);
        const int db = dest[b];
        const float2 dsx = *(const float2*)(segs_src + 2 * (size_t)db);
        const float2 sx = *(const float2*)(segs_src + 2 * (size_t)s);
        const float2 tx = *(const float2*)(segs_trg + 2 * (size_t)s);
        const float v1x = dsx.x - sx.x, v1y = dsx.y - sx.y;
        const float v2x = tx.x - sx.x, v2y = tx.y - sx.y;
        const float num = v1x * v2x + v1y * v2y;
        const float den = fmaxf(sqrtf(v1x * v1x + v1y * v1y) *
                                sqrtf(v2x * v2x + v2y * v2y), 1e-8f);
        const float cosv = num / den;
        const float tf = traffic_pop[(size_t)s * TSLOTS + tt[b]];
        const float e0 = fmaf(cosv, cand_w[0], fmaf(tf, cand_w[1], cand_b[0]));
        const float e1 = fmaf(cosv, cand_w[2], fmaf(tf, cand_w[3], cand_b[1]));
        const float e2 = fmaf(cosv, cand_w[4], fmaf(tf, cand_w[5], cand_b[2]));
        const float e3 = fmaf(cosv, cand_w[6], fmaf(tf, cand_w[7], cand_b[3]));
        list_t[e] = e0 * t4.x + e1 * t4.y + e2 * t4.z + e3 * t4.w + dense_b[s];
    }
    __syncthreads();

    // ---- phase 3: per-entry wave dot, 2-way unrolled (16 waves) ----
    const int wave = tid >> 6;
    const int lane = tid & 63;
    const int ll = (lane < 63) ? lane : 62;
    for (int e0 = wave; e0 < nh; e0 += 32) {
        const int e1 = e0 + 16;
        const unsigned i0 = list_i[e0];
        const int s0 = list_s[e0];
        const int b0 = (int)(i0 >> 6);
        const float4 dw0 = *(const float4*)(dense_w + (size_t)s0 * DWC + ll * 4);
        const float4 o0  = *(const float4*)(out_ws + (size_t)b0 * DM8 + ll * 4);
        unsigned i1 = 0; int s1 = 0, b1v = 0;
        float4 dw1 = {0.f,0.f,0.f,0.f}, o1 = {0.f,0.f,0.f,0.f};
        const bool has1 = (e1 < nh);
        if (has1) {
            i1 = list_i[e1];
            s1 = list_s[e1];
            b1v = (int)(i1 >> 6);
            dw1 = *(const float4*)(dense_w + (size_t)s1 * DWC + ll * 4);
            o1  = *(const float4*)(out_ws + (size_t)b1v * DM8 + ll * 4);
        }
        float p0 = (lane == 63) ? list_t[e0]
                 : dw0.x * o0.x + dw0.y * o0.y + dw0.z * o0.z + dw0.w * o0.w;
        float p1 = (has1 && lane == 63) ? list_t[e1]
                 : dw1.x * o1.x + dw1.y * o1.y + dw1.z * o1.z + dw1.w * o1.w;
#pragma unroll
        for (int sft = 1; sft < 64; sft <<= 1) {
            p0 += __shfl_xor(p0, sft, 64);
            p1 += __shfl_xor(p1, sft, 64);
        }
        if (lane == 0) {
            logits[i0] = p0;
            if (has1) logits[i1] = p1;
        }
    }
}

extern "C" void kernel_launch(void* const* d_in, const int* in_sizes, int n_in,
                              void* d_out, int out_size, void* d_ws, size_t ws_size,
                              hipStream_t stream) {
    const int*   src         = (const int*)d_in[0];
    const int*   dest        = (const int*)d_in[1];
    const int*   tt          = (const int*)d_in[2];
    const int*   candidates  = (const int*)d_in[3];
    const float* offset      = (const float*)d_in[4];
    const float* emb_feat    = (const float*)d_in[5];
    const float* emb_dest    = (const float*)d_in[6];
    const float* w1          = (const float*)d_in[7];
    const float* b1          = (const float*)d_in[8];
    const float* bn_gamma    = (const float*)d_in[9];
    const float* bn_beta     = (const float*)d_in[10];
    const float* bn_mean     = (const float*)d_in[11];
    const float* bn_var      = (const float*)d_in[12];
    const float* w2          = (const float*)d_in[13];
    const float* b2          = (const float*)d_in[14];
    const float* dense_w     = (const float*)d_in[15];
    const float* dense_b     = (const float*)d_in[16];
    const float* cand_w      = (const float*)d_in[17];
    const float* cand_b      = (const float*)d_in[18];
    const float* segs_src    = (const float*)d_in[19];
    const float* segs_trg    = (const float*)d_in[20];
    const float* traffic_pop = (const float*)d_in[21];

    float* out_ws = (float*)d_ws;        // 4096*256 f32 = 4 MB
    float* logits = (float*)d_out;       // 4096*64 f32

    mlp_kernel<<<BATCH / 16, 512, 0, stream>>>(
        src, dest, offset, emb_feat, emb_dest,
        w1, b1, bn_gamma, bn_beta, bn_mean, bn_var, w2, b2, out_ws);

    logits_stream_kernel<<<SBLK, STHR, 0, stream>>>(
        dest, tt, candidates, dense_w, dense_b, cand_w, cand_b,
        segs_src, segs_trg, traffic_pop, out_ws, logits);
}

// Round 12
// 83.135 us; speedup vs baseline: 1.3529x; 1.3529x over previous
//
#include <hip/hip_runtime.h>

// KeySegPred — round 12: r8 structure, ONE change — loop-free conv.
//   K1 conv_kernel (12305+32 x 256): each thread converts exactly ONE 8-float chunk
//      (2x float4 load -> 1x 16B bf16x8 store); no grid-stride loop. Tail blocks
//      convert w1/w2 to bf16 tables.
//   K2 mlp_kernel    (256x512) : MFMA MLP from bf16 tables (r8-identical, ~24 us).
//   K3 logits_kernel (4096x256): 16-deep bf16 row gather + LDS transpose-reduce (~5 us).
//   Fallback (ws too small): inline-convert MLP + fp32 logits gather.

#define BATCH 4096
#define DSEG 128
#define DS_ 258
#define DM7 512
#define DM8 256
#define NCAND 64
#define DWC 252
#define TSLOTS 96
#define SEGN 100000
#define DWBLK 12305   // ceil(3,150,000 / 256) one-chunk-per-thread blocks

typedef short bf16x8 __attribute__((ext_vector_type(8)));
typedef short bf16x4 __attribute__((ext_vector_type(4)));
typedef float f32x4 __attribute__((ext_vector_type(4)));

static __device__ __forceinline__ short f2bf(float f) {
    union { float f; unsigned u; } v; v.f = f;
    unsigned r = (v.u + 0x7FFFu + ((v.u >> 16) & 1u)) >> 16;  // RNE
    return (short)r;
}
static __device__ __forceinline__ bf16x4 cvt4(float4 v) {
    bf16x4 s;
    s[0] = f2bf(v.x); s[1] = f2bf(v.y); s[2] = f2bf(v.z); s[3] = f2bf(v.w);
    return s;
}
static __device__ __forceinline__ bf16x8 pack8(float4 a, float4 b) {
    bf16x8 s;
    s[0] = f2bf(a.x); s[1] = f2bf(a.y); s[2] = f2bf(a.z); s[3] = f2bf(a.w);
    s[4] = f2bf(b.x); s[5] = f2bf(b.y); s[6] = f2bf(b.z); s[7] = f2bf(b.w);
    return s;
}
static __device__ __forceinline__ float bfu2f(unsigned u16) {
    union { unsigned u; float f; } v; v.u = u16 << 16; return v.f;
}

__global__ __launch_bounds__(256) void conv_kernel(
    const float* __restrict__ dense_w, const float* __restrict__ w1,
    const float* __restrict__ w2,
    short* __restrict__ wtab, short* __restrict__ w1tab, short* __restrict__ w2tab)
{
    const int tid = threadIdx.x;
    if (blockIdx.x < DWBLK) {
        // ONE chunk per thread: 8 floats in (2x float4), 8 bf16 out (1x 16B store)
        const size_t c = (size_t)blockIdx.x * 256 + tid;
        const size_t n8 = (size_t)SEGN * DWC / 8;        // 3,150,000
        if (c < n8) {
            const float4* __restrict__ s4 = (const float4*)dense_w;
            const float4 a = s4[2 * c];
            const float4 b = s4[2 * c + 1];
            ((bf16x8*)wtab)[c] = pack8(a, b);
        }
    } else if (blockIdx.x < DWBLK + 16) {
        // w1tab[n][k<256]; fp32 tail cols 256,257 kept exact elsewhere
        for (int e = (blockIdx.x - DWBLK) * 256 + tid; e < 32768; e += 4096) {
            const int n = e >> 6, k4 = e & 63;
            const float4 v = *(const float4*)(w1 + (size_t)n * DS_ + k4 * 4);
            *(bf16x4*)(w1tab + n * 256 + k4 * 4) = cvt4(v);
        }
    } else {
        for (int e = (blockIdx.x - DWBLK - 16) * 256 + tid; e < 32768; e += 4096) {
            const float4 v = *(const float4*)(w2 + (size_t)e * 4);
            *(bf16x4*)(w2tab + (size_t)e * 4) = cvt4(v);
        }
    }
}

template <bool TAB>
__global__ __launch_bounds__(512) void mlp_kernel_t(
    const int* __restrict__ src, const int* __restrict__ dest,
    const float* __restrict__ offset,
    const float* __restrict__ emb_feat, const float* __restrict__ emb_dest,
    const float* __restrict__ w1, const float* __restrict__ b1,
    const float* __restrict__ bn_gamma, const float* __restrict__ bn_beta,
    const float* __restrict__ bn_mean, const float* __restrict__ bn_var,
    const float* __restrict__ w2, const float* __restrict__ b2,
    const short* __restrict__ w1tab, const short* __restrict__ w2tab,
    float* __restrict__ out_ws)
{
    __shared__ __align__(16) short hlds[16][520];
    const int tid = threadIdx.x;
    const int w    = tid >> 6;     // wave 0..7
    const int lane = tid & 63;
    const int lg   = lane >> 4;    // 0..3
    const int lr   = lane & 15;    // 0..15
    const int b0   = blockIdx.x * 16;

    const int si = src[b0 + lr];
    const int di = dest[b0 + lr];
    const float* fb = emb_feat + (size_t)si * DSEG;
    const float* db = emb_dest + (size_t)di * DSEG;
    bf16x8 a1[8];
#pragma unroll
    for (int s = 0; s < 8; ++s) {
        const float* p = (s < 4) ? (fb + s * 32 + lg * 8)
                                 : (db + (s - 4) * 32 + lg * 8);
        const float4 x = *(const float4*)p;
        const float4 y = *(const float4*)(p + 4);
        a1[s] = pack8(x, y);
    }
    float off1[4], off2[4];
#pragma unroll
    for (int q = 0; q < 4; ++q) {
        const float4 o = *(const float4*)(offset + (size_t)(b0 + lg * 4 + q) * 4);
        off1[q] = o.y; off2[q] = o.z;
    }

#pragma unroll
    for (int nt = 0; nt < 4; ++nt) {
        const int n = (w * 4 + nt) * 16 + lr;
        f32x4 acc = {0.f, 0.f, 0.f, 0.f};
#pragma unroll
        for (int s = 0; s < 8; ++s) {
            bf16x8 bb;
            if (TAB) {
                bb = *(const bf16x8*)(w1tab + (size_t)n * 256 + s * 32 + lg * 8);
            } else {
                const float* p = w1 + (size_t)n * DS_ + s * 32 + lg * 8;
                const float2 x0 = *(const float2*)(p);
                const float2 x1 = *(const float2*)(p + 2);
                const float2 x2 = *(const float2*)(p + 4);
                const float2 x3 = *(const float2*)(p + 6);
                bb[0] = f2bf(x0.x); bb[1] = f2bf(x0.y); bb[2] = f2bf(x1.x); bb[3] = f2bf(x1.y);
                bb[4] = f2bf(x2.x); bb[5] = f2bf(x2.y); bb[6] = f2bf(x3.x); bb[7] = f2bf(x3.y);
            }
            acc = __builtin_amdgcn_mfma_f32_16x16x32_bf16(a1[s], bb, acc, 0, 0, 0);
        }
        const float2 wtail = *(const float2*)(w1 + (size_t)n * DS_ + 256);
        const float scale = bn_gamma[n] / sqrtf(bn_var[n] + 1e-6f);
        const float shift = bn_beta[n] - bn_mean[n] * scale;
        const float bias  = b1[n];
#pragma unroll
        for (int q = 0; q < 4; ++q) {
            float v = acc[q] + bias + off1[q] * wtail.x + off2[q] * wtail.y;
            v = fmaf(v, scale, shift);
            v = fmaxf(v, 0.f);
            hlds[lg * 4 + q][n] = f2bf(v);
        }
    }
    __syncthreads();

    bf16x8 a2[16];
#pragma unroll
    for (int s = 0; s < 16; ++s) {
        a2[s] = *(const bf16x8*)&hlds[lr][s * 32 + lg * 8];
    }
#pragma unroll
    for (int nt = 0; nt < 2; ++nt) {
        const int n = (w * 2 + nt) * 16 + lr;
        f32x4 acc = {0.f, 0.f, 0.f, 0.f};
#pragma unroll
        for (int s = 0; s < 16; ++s) {
            bf16x8 bb;
            if (TAB) {
                bb = *(const bf16x8*)(w2tab + (size_t)n * 512 + s * 32 + lg * 8);
            } else {
                const float4 x = *(const float4*)(w2 + (size_t)n * DM7 + s * 32 + lg * 8);
                const float4 y = *(const float4*)(w2 + (size_t)n * DM7 + s * 32 + lg * 8 + 4);
                bb = pack8(x, y);
            }
            acc = __builtin_amdgcn_mfma_f32_16x16x32_bf16(a2[s], bb, acc, 0, 0, 0);
        }
        const float bias = b2[n];
#pragma unroll
        for (int q = 0; q < 4; ++q) {
            out_ws[(size_t)(b0 + lg * 4 + q) * DM8 + n] = acc[q] + bias;
        }
    }
}

template <bool BF16TAB>
__global__ __launch_bounds__(256) void logits_kernel_t(
    const int* __restrict__ dest, const int* __restrict__ tt,
    const int* __restrict__ candidates,
    const float* __restrict__ dense_w, const unsigned short* __restrict__ wtab,
    const float* __restrict__ dense_b,
    const float* __restrict__ cand_w, const float* __restrict__ cand_b,
    const float* __restrict__ segs_src, const float* __restrict__ segs_trg,
    const float* __restrict__ traffic_pop,
    const float* __restrict__ out_ws,
    float* __restrict__ logits)
{
    __shared__ float plds[4][16][67];
    const int b = blockIdx.x;
    const int tid = threadIdx.x;
    const int wave = tid >> 6;
    const int lane = tid & 63;
    const int mbase = wave * 16;

    int candv = 0;
    if (lane < 16) candv = candidates[b * NCAND + mbase + lane];

    const int ll = (lane < 63) ? lane : 62;
    float4 dwf[16];
    uint2  dwb[16];
    if (BF16TAB) {
#pragma unroll
        for (int i = 0; i < 16; ++i) {
            const int ci = __shfl(candv, i, 64);
            dwb[i] = *(const uint2*)(wtab + (size_t)ci * DWC + ll * 4);  // 8B/lane
        }
    } else {
#pragma unroll
        for (int i = 0; i < 16; ++i) {
            const int ci = __shfl(candv, i, 64);
            dwf[i] = *(const float4*)(dense_w + (size_t)ci * DWC + ll * 4);
        }
    }

    float4 o4 = *(const float4*)(out_ws + (size_t)b * DM8 + ll * 4);
    if (lane == 63) { o4.x = 0.f; o4.y = 0.f; o4.z = 0.f; o4.w = 0.f; }

    float tail = 0.f;
    if (lane < 16) {
        const float4 t4 = *(const float4*)(out_ws + (size_t)b * DM8 + DWC);
        const int db = dest[b];
        const float2 dsx = *(const float2*)(segs_src + 2 * (size_t)db);
        const float2 sx = *(const float2*)(segs_src + 2 * (size_t)candv);
        const float2 tx = *(const float2*)(segs_trg + 2 * (size_t)candv);
        const float v1x = dsx.x - sx.x, v1y = dsx.y - sx.y;
        const float v2x = tx.x - sx.x, v2y = tx.y - sx.y;
        const float num = v1x * v2x + v1y * v2y;
        const float den = fmaxf(sqrtf(v1x * v1x + v1y * v1y) *
                                sqrtf(v2x * v2x + v2y * v2y), 1e-8f);
        const float cosv = num / den;
        const float tf = traffic_pop[(size_t)candv * TSLOTS + tt[b]];
        const float e0 = fmaf(cosv, cand_w[0], fmaf(tf, cand_w[1], cand_b[0]));
        const float e1 = fmaf(cosv, cand_w[2], fmaf(tf, cand_w[3], cand_b[1]));
        const float e2 = fmaf(cosv, cand_w[4], fmaf(tf, cand_w[5], cand_b[2]));
        const float e3 = fmaf(cosv, cand_w[6], fmaf(tf, cand_w[7], cand_b[3]));
        tail = e0 * t4.x + e1 * t4.y + e2 * t4.z + e3 * t4.w + dense_b[candv];
    }

#pragma unroll
    for (int i = 0; i < 16; ++i) {
        float p;
        if (BF16TAB) {
            p =      bfu2f(dwb[i].x & 0xFFFFu) * o4.x;
            p = fmaf(bfu2f(dwb[i].x >> 16),      o4.y, p);
            p = fmaf(bfu2f(dwb[i].y & 0xFFFFu),  o4.z, p);
            p = fmaf(bfu2f(dwb[i].y >> 16),      o4.w, p);
        } else {
            p = dwf[i].x * o4.x + dwf[i].y * o4.y + dwf[i].z * o4.z + dwf[i].w * o4.w;
        }
        plds[wave][i][lane] = p;
    }
    __syncthreads();

    const int cc = lane >> 2;
    const int qq = lane & 3;
    float s = 0.f;
#pragma unroll
    for (int j = 0; j < 16; ++j) s += plds[wave][cc][qq * 16 + j];
    s += __shfl_xor(s, 1, 64);
    s += __shfl_xor(s, 2, 64);
    const float tl = __shfl(tail, cc, 64);
    if (qq == 0) logits[(size_t)b * NCAND + mbase + cc] = s + tl;
}

extern "C" void kernel_launch(void* const* d_in, const int* in_sizes, int n_in,
                              void* d_out, int out_size, void* d_ws, size_t ws_size,
                              hipStream_t stream) {
    const int*   src         = (const int*)d_in[0];
    const int*   dest        = (const int*)d_in[1];
    const int*   tt          = (const int*)d_in[2];
    const int*   candidates  = (const int*)d_in[3];
    const float* offset      = (const float*)d_in[4];
    const float* emb_feat    = (const float*)d_in[5];
    const float* emb_dest    = (const float*)d_in[6];
    const float* w1          = (const float*)d_in[7];
    const float* b1          = (const float*)d_in[8];
    const float* bn_gamma    = (const float*)d_in[9];
    const float* bn_beta     = (const float*)d_in[10];
    const float* bn_mean     = (const float*)d_in[11];
    const float* bn_var      = (const float*)d_in[12];
    const float* w2          = (const float*)d_in[13];
    const float* b2          = (const float*)d_in[14];
    const float* dense_w     = (const float*)d_in[15];
    const float* dense_b     = (const float*)d_in[16];
    const float* cand_w      = (const float*)d_in[17];
    const float* cand_b      = (const float*)d_in[18];
    const float* segs_src    = (const float*)d_in[19];
    const float* segs_trg    = (const float*)d_in[20];
    const float* traffic_pop = (const float*)d_in[21];

    float* out_ws = (float*)d_ws;
    const size_t OUT_WS_BYTES = (size_t)BATCH * DM8 * 4;        //  4,194,304
    const size_t WTAB_BYTES   = (size_t)SEGN * DWC * 2;         // 50,400,000
    const size_t W1TAB_BYTES  = (size_t)DM7 * 256 * 2;          //    262,144
    const size_t W2TAB_BYTES  = (size_t)DM8 * DM7 * 2;          //    262,144
    short* wtab  = (short*)((char*)d_ws + OUT_WS_BYTES);
    short* w1tab = (short*)((char*)d_ws + OUT_WS_BYTES + WTAB_BYTES);
    short* w2tab = (short*)((char*)d_ws + OUT_WS_BYTES + WTAB_BYTES + W1TAB_BYTES);
    const bool use_tab =
        ws_size >= OUT_WS_BYTES + WTAB_BYTES + W1TAB_BYTES + W2TAB_BYTES;
    float* logits = (float*)d_out;

    if (use_tab) {
        conv_kernel<<<DWBLK + 32, 256, 0, stream>>>(
            dense_w, w1, w2, wtab, w1tab, w2tab);
        mlp_kernel_t<true><<<BATCH / 16, 512, 0, stream>>>(
            src, dest, offset, emb_feat, emb_dest,
            w1, b1, bn_gamma, bn_beta, bn_mean, bn_var, w2, b2, w1tab, w2tab, out_ws);
        logits_kernel_t<true><<<BATCH, 256, 0, stream>>>(
            dest, tt, candidates, dense_w, (const unsigned short*)wtab, dense_b,
            cand_w, cand_b, segs_src, segs_trg, traffic_pop, out_ws, logits);
    } else {
        mlp_kernel_t<false><<<BATCH / 16, 512, 0, stream>>>(
            src, dest, offset, emb_feat, emb_dest,
            w1, b1, bn_gamma, bn_beta, bn_mean, bn_var, w2, b2, w1tab, w2tab, out_ws);
        logits_kernel_t<false><<<BATCH, 256, 0, stream>>>(
            dest, tt, candidates, dense_w, (const unsigned short*)wtab, dense_b,
            cand_w, cand_b, segs_src, segs_trg, traffic_pop, out_ws, logits);
    }
}